// Round 6
// baseline (3111.430 us; speedup 1.0000x reference)
//
#include <hip/hip_runtime.h>
#include <math.h>

// Problem constants (from reference)
#define B_   8
#define T_   128
#define E_   256
#define H_   512
#define G_   2048
#define NWG  128           // 1 WG per CU, co-resident
#define NTHR 1024          // 16 waves: wave = (batch, half)
#define NCOL 4             // h-columns owned per WG (128*4 = 512)
#define NGC  16            // gate columns per WG
#define XPITCH 1025        // LDS pitch, column-major X (conflict-free)

typedef unsigned long long u64;

// ---------------------------------------------------------------------------
// ALGEBRA (unchanged): softmax sums to 1 over t and h_shared is t-invariant =>
// Rt == h_last; attention path is dead. Compute:
//   h_last = sharedLSTM(emb); M = h_last @ Wmh_t; out = taskLSTM(emb; X2+h@Whh_t+M)
//
// R6 = R5 minus the spill: R5 needed 128 weight VGPRs/lane -> compiler spilled
// to scratch (VGPR_Count=104 < 128, FETCH +38MB, 10us/step). Now 2 waves per
// batch: wave (b, half) owns 8 gate-cols (4 gates x 2 h-cols) -> 64 weight
// VGPRs/lane, hard-capped at 128 via __launch_bounds__(1024, 4).
//  - lane l holds W[k=l*8..+8][its 8 cols] in 64 VGPRs; h[b] payload arrives
//    in registers from a coalesced agent-relaxed load (no LDS round-trip).
//  - octet value-halving butterfly (9 shuffle-adds) -> lane holds col
//    c8 = bitrev3(l&7); quad gate-gather as R5 (i,g,f,o at quad pos 0,1,2,3).
//  - publish: both halves store img; half1 does vmcnt(0) then LDS pair_flag;
//    half0 spins on pair_flag, vmcnt(0) for its own stores, then publishes the
//    per-(b,wg) global flag. Data is at the device coherence point before the
//    flag in real time -> agent observer of flag sees both halves' data.
//  - flags packed u64[b][64] (wg low32, wg+64 high32): one poll load per lane.
//  - no-overwrite: publishing gen g+1 data-depends on having consumed gen g,
//    so flags>=g+1 everywhere => all reads of g done => gen g+2 write safe.
// ---------------------------------------------------------------------------

__device__ __forceinline__ float sigf(float x) { return 1.0f / (1.0f + expf(-x)); }

#define IMG_F 8192          // img: float[2][4096]; flags: u64[8][64] after it

__global__ void init_ws(float* ws) {
  u64* flags = (u64*)(ws + IMG_F);
  int i = blockIdx.x * blockDim.x + threadIdx.x;
  if (i < B_ * 64) flags[i] = 0ull;    // ws poisoned 0xAA -> zero flags
}

// Stage 512x16 col-slice of a (512 x 2048) recurrent weight, K-MAJOR:
// Wl2[k*16 + c] = W[k][(c>>2)*H + wg*4 + (c&3)]
__device__ __forceinline__ void load_wk(const float* __restrict__ W, int wg,
                                        float* __restrict__ Wl2) {
  for (int idx = threadIdx.x; idx < H_ * NGC; idx += NTHR) {
    int k = idx >> 4, c = idx & 15;
    Wl2[idx] = W[k * G_ + ((c >> 2) * H_ + wg * NCOL + (c & 3))];
  }
}

// Per-lane register weights: wrk[kk*8 + (g*2+u)] = W[l*8+kk][g*4 + half*2 + u]
__device__ __forceinline__ void load_wrk(const float* __restrict__ Wl2, int l,
                                         int half, float* __restrict__ wrk) {
#pragma unroll
  for (int kk = 0; kk < 8; ++kk) {
    const float* row = Wl2 + (l * 8 + kk) * 16 + half * 2;
#pragma unroll
    for (int gg = 0; gg < 4; ++gg) {
      wrk[kk * 8 + gg * 2 + 0] = row[gg * 4 + 0];
      wrk[kk * 8 + gg * 2 + 1] = row[gg * 4 + 1];
    }
  }
}

// Poll packed flags, load h[b] payload into registers, dot with wrk,
// octet butterfly-reduce. Returns full col sum for c8 = bitrev3(l&7).
__device__ __forceinline__ float rec_dot(const float* __restrict__ img,
                                         const u64* __restrict__ flags,
                                         unsigned gen, int b, int l,
                                         const float* __restrict__ wrk) {
  const u64* fl = flags + b * 64;
  for (;;) {
    u64 v = __hip_atomic_load(&fl[l], __ATOMIC_RELAXED, __HIP_MEMORY_SCOPE_AGENT);
    if ((unsigned)v >= gen && (unsigned)(v >> 32) >= gen) break;
    __builtin_amdgcn_s_sleep(1);
  }
  const u64* src = (const u64*)(img + (gen & 1u) * 4096 + b * H_) + (size_t)l * 4;
  u64 v[4];
#pragma unroll
  for (int j = 0; j < 4; ++j)
    v[j] = __hip_atomic_load(src + j, __ATOMIC_RELAXED, __HIP_MEMORY_SCOPE_AGENT);
  float h8[8];
#pragma unroll
  for (int j = 0; j < 4; ++j) {
    h8[2 * j]     = __uint_as_float((unsigned)v[j]);
    h8[2 * j + 1] = __uint_as_float((unsigned)(v[j] >> 32));
  }

  float acc[8];
#pragma unroll
  for (int c = 0; c < 8; ++c) acc[c] = 0.0f;
#pragma unroll
  for (int kk = 0; kk < 8; ++kk) {
    float hv = h8[kk];
#pragma unroll
    for (int c = 0; c < 8; ++c) acc[c] += hv * wrk[kk * 8 + c];
  }

  // value-halving butterfly: final col index c8 = 4*(l&1) + 2*((l>>1)&1) + ((l>>2)&1)
  float o4[4];
#pragma unroll
  for (int j = 0; j < 4; ++j) {
    float send = (l & 1) ? acc[j] : acc[4 + j];
    float keep = (l & 1) ? acc[4 + j] : acc[j];
    o4[j] = keep + __shfl_xor(send, 1);
  }
  float o2[2];
#pragma unroll
  for (int j = 0; j < 2; ++j) {
    float send = (l & 2) ? o4[j] : o4[2 + j];
    float keep = (l & 2) ? o4[2 + j] : o4[j];
    o2[j] = keep + __shfl_xor(send, 2);
  }
  float send = (l & 4) ? o2[0] : o2[1];
  float keep = (l & 4) ? o2[1] : o2[0];
  float s = keep + __shfl_xor(send, 4);
  s += __shfl_xor(s, 8);
  s += __shfl_xor(s, 16);
  s += __shfl_xor(s, 32);
  return s;
}

// Publish gen gw: img stores (st lanes), drain, pair handshake, global flag.
__device__ __forceinline__ void publish(float* __restrict__ img,
                                        u64* __restrict__ flags,
                                        unsigned* __restrict__ pair_flag,
                                        int wg, int b, int half, int l, int hc,
                                        bool st, float hn, unsigned gw) {
  if (st)
    __hip_atomic_store(img + (gw & 1u) * 4096 + b * H_ + wg * NCOL + hc, hn,
                       __ATOMIC_RELAXED, __HIP_MEMORY_SCOPE_AGENT);
  __builtin_amdgcn_s_waitcnt(0x0f70);   // vmcnt(0): own stores at coherence pt
  if (half == 1) {
    if (l == 0)
      __hip_atomic_store(&pair_flag[b], gw, __ATOMIC_RELAXED,
                         __HIP_MEMORY_SCOPE_WORKGROUP);
  } else if (l == 0) {
    while (__hip_atomic_load(&pair_flag[b], __ATOMIC_RELAXED,
                             __HIP_MEMORY_SCOPE_WORKGROUP) < gw)
      __builtin_amdgcn_s_sleep(1);
    unsigned* fp = (unsigned*)(flags + b * 64 + (wg & 63)) + (wg >> 6);
    __hip_atomic_store(fp, gw, __ATOMIC_RELAXED, __HIP_MEMORY_SCOPE_AGENT);
  }
}

// X[c][r] = sum_e emb[r][e]*Wih[e][col(c)] + bias[col(c)], r = t*8+b, col-major.
__device__ __forceinline__ void compute_X(const float* __restrict__ Wih,
                                          const float* __restrict__ bias,
                                          const int* __restrict__ tokens,
                                          const float* __restrict__ embed,
                                          int wg, float* __restrict__ Wbuf,
                                          float* __restrict__ Xlds,
                                          float* __restrict__ bias_lds) {
  const int tid = threadIdx.x;
  for (int idx = tid; idx < E_ * NGC; idx += NTHR) {     // 4096
    int e = idx >> 4, c = idx & 15;
    Wbuf[idx] = Wih[e * G_ + ((c >> 2) * H_ + wg * NCOL + (c & 3))];
  }
  if (tid < NGC) bias_lds[tid] = bias[(tid >> 2) * H_ + wg * NCOL + (tid & 3)];
  __syncthreads();

  const int r = tid;                                     // one row per thread
  const int tok = tokens[(r & 7) * T_ + (r >> 3)];       // tokens (B,T); r=t*8+b
  const float4* er = (const float4*)(embed + (size_t)tok * E_);
  float acc[NGC];
#pragma unroll
  for (int cc = 0; cc < NGC; ++cc) acc[cc] = bias_lds[cc];

  for (int ec = 0; ec < E_ / 4; ++ec) {
    float4 ev = er[ec];
    const float4* w4 = (const float4*)(Wbuf + ec * 64);
#pragma unroll
    for (int eo = 0; eo < 4; ++eo) {
      float wrow[16];
      *(float4*)(wrow + 0)  = w4[eo * 4 + 0];            // broadcast LDS reads
      *(float4*)(wrow + 4)  = w4[eo * 4 + 1];
      *(float4*)(wrow + 8)  = w4[eo * 4 + 2];
      *(float4*)(wrow + 12) = w4[eo * 4 + 3];
      float e_v = reinterpret_cast<const float*>(&ev)[eo];
#pragma unroll
      for (int cc = 0; cc < NGC; ++cc) acc[cc] += e_v * wrow[cc];
    }
  }
#pragma unroll
  for (int cc = 0; cc < NGC; ++cc)
    Xlds[cc * XPITCH + r] = acc[cc];                     // 2-way max (free)
}

__global__ __launch_bounds__(NTHR, 4) void lstm_all(
    const int* __restrict__ tokens, const float* __restrict__ embed,
    const float* __restrict__ Wih_s, const float* __restrict__ Whh_s,
    const float* __restrict__ b_s,
    const float* __restrict__ Wih_t, const float* __restrict__ Whh_t,
    const float* __restrict__ Wmh_t, const float* __restrict__ b_t,
    float* __restrict__ out, float* __restrict__ ws) {
  __shared__ float Wl2[H_ * NGC];        // 32 KB k-major weights / Wih staging
  __shared__ float Xlds[NGC * XPITCH];   // 65.6 KB col-major X
  __shared__ float bias_lds[NGC];
  __shared__ unsigned pair_flag[B_];

  const int tid  = threadIdx.x;
  const int wg   = blockIdx.x;
  const int l    = tid & 63;
  const int wv   = tid >> 6;             // wave 0..15
  const int b    = wv >> 1;              // batch
  const int half = wv & 1;               // h-col pair
  float* img  = ws;                      // float[2][4096]
  u64*   flags = (u64*)(ws + IMG_F);

  const int p  = l & 3;                                       // quad pos
  const int c8 = ((l & 1) << 2) | (l & 2) | ((l >> 2) & 1);   // owned col
  const int u  = c8 & 1;
  const int g  = c8 >> 1;                // gate = bitrev2(p)
  const int hc = half * 2 + u;           // global h-col 0..3
  const bool st = (l == 0) || (l == 4);  // l=0 -> u=0, l=4 -> u=1

  float wrk[64];

  if (tid < B_) pair_flag[tid] = 0u;
  // ---------------- Phase A1: X1 = emb @ Wih_s + b_s
  compute_X(Wih_s, b_s, tokens, embed, wg, Wl2, Xlds, bias_lds);
  __syncthreads();
  load_wk(Whh_s, wg, Wl2);
  __syncthreads();
  load_wrk(Wl2, l, half, wrk);

  // ---------------- Phase B: shared LSTM (only h_last live); gens 1..128
  float c_reg = 0.0f;
  for (int t = 0; t < T_; ++t) {
    float d = (t > 0) ? rec_dot(img, flags, (unsigned)t, b, l, wrk) : 0.0f;
    float pre = d + Xlds[(g * 4 + hc) * XPITCH + t * 8 + b];
    float v1 = __shfl_xor(pre, 1), v2 = __shfl_xor(pre, 2), v3 = __shfl_xor(pre, 3);
    auto pick = [&](int m) { return m == 0 ? pre : (m == 1 ? v1 : (m == 2 ? v2 : v3)); };
    float gi = pick(p ^ 0), gg = pick(p ^ 1), gf = pick(p ^ 2), go = pick(p ^ 3);
    float cn = sigf(gf) * c_reg + sigf(gi) * tanhf(gg);
    float hn = sigf(go) * tanhf(cn);
    c_reg = cn;
    publish(img, flags, pair_flag, wg, b, half, l, hc, st, hn, (unsigned)t + 1u);
  }

  // ---------------- M = h_last @ Wmh_t (consume gen 128)
  __syncthreads();
  load_wk(Wmh_t, wg, Wl2);
  __syncthreads();
  load_wrk(Wl2, l, half, wrk);
  float Mreg = rec_dot(img, flags, 128u, b, l, wrk);

  // ---------------- Phase A2: X2 = emb @ Wih_t + b_t
  __syncthreads();
  compute_X(Wih_t, b_t, tokens, embed, wg, Wl2, Xlds, bias_lds);
  __syncthreads();
  load_wk(Whh_t, wg, Wl2);
  __syncthreads();
  load_wrk(Wl2, l, half, wrk);

  // ---------------- Phase C: task LSTM; gens 129..255; out every step
  c_reg = 0.0f;
  for (int t = 0; t < T_; ++t) {
    float d = (t > 0) ? rec_dot(img, flags, 128u + (unsigned)t, b, l, wrk) : 0.0f;
    float pre = d + Xlds[(g * 4 + hc) * XPITCH + t * 8 + b] + Mreg;
    float v1 = __shfl_xor(pre, 1), v2 = __shfl_xor(pre, 2), v3 = __shfl_xor(pre, 3);
    auto pick = [&](int m) { return m == 0 ? pre : (m == 1 ? v1 : (m == 2 ? v2 : v3)); };
    float gi = pick(p ^ 0), gg = pick(p ^ 1), gf = pick(p ^ 2), go = pick(p ^ 3);
    float cn = sigf(gf) * c_reg + sigf(gi) * tanhf(gg);
    float hn = sigf(go) * tanhf(cn);
    c_reg = cn;
    if (st) out[b * (T_ * H_) + t * H_ + wg * NCOL + hc] = hn;
    if (t < T_ - 1)
      publish(img, flags, pair_flag, wg, b, half, l, hc, st, hn, 129u + (unsigned)t);
  }
}

extern "C" void kernel_launch(void* const* d_in, const int* in_sizes, int n_in,
                              void* d_out, int out_size, void* d_ws, size_t ws_size,
                              hipStream_t stream) {
  const int*   tokens = (const int*)d_in[0];
  // d_in[1] = TASK (unused)
  const float* embed  = (const float*)d_in[2];
  const float* Wih_s  = (const float*)d_in[3];
  const float* Whh_s  = (const float*)d_in[4];
  const float* b_s    = (const float*)d_in[5];
  // d_in[6..9] = Ws_w, Ws_b, Us_w, Us_b -> dead (attention collapses)
  const float* Wih_t  = (const float*)d_in[10];
  const float* Whh_t  = (const float*)d_in[11];
  const float* Wmh_t  = (const float*)d_in[12];
  const float* b_t    = (const float*)d_in[13];
  float* out = (float*)d_out;
  float* ws  = (float*)d_ws;

  hipLaunchKernelGGL(init_ws, dim3(1), dim3(512), 0, stream, ws);
  hipLaunchKernelGGL(lstm_all, dim3(NWG), dim3(NTHR), 0, stream,
                     tokens, embed, Wih_s, Whh_s, b_s,
                     Wih_t, Whh_t, Wmh_t, b_t, out, ws);
}

// Round 7
// 2606.262 us; speedup vs baseline: 1.1938x; 1.1938x over previous
//
#include <hip/hip_runtime.h>
#include <math.h>

// Problem constants (from reference)
#define B_   8
#define T_   128
#define E_   256
#define H_   512
#define G_   2048
#define NWG  128           // 1 WG per CU, co-resident
#define NTHR 512           // 8 waves = 8 batches
#define NCOL 4             // h-columns owned per WG (128*4 = 512)
#define NGC  16            // gate columns per WG
#define XPITCH 1025        // LDS pitch, column-major X (conflict-free)

typedef unsigned long long u64;

// ---------------------------------------------------------------------------
// ALGEBRA (unchanged): softmax sums to 1 over t and h_shared is t-invariant =>
// Rt == h_last; attention path dead. Compute:
//   h_last = sharedLSTM(emb); M = h_last @ Wmh_t; out = taskLSTM(emb; X2+h@Whh_t+M)
//
// R7 = R5 structure with two fixes:
//  (1) amdgpu_waves_per_eu(2,2): R4/R5/R6 all SPILLED the register weight
//      cache (allocator targets its own occupancy: 128 regs @512thr, 64 @1024)
//      -> scratch traffic dominated the serial path. 8 waves = 2/EU -> 256-reg
//      budget; R5's ~190-reg working set now fits.
//  (2) producer publishes WITHOUT vmcnt drain: payload dwords carry mantissa-
//      LSB parity tags (gen>>1)&1, double-buffered by gen&1 (stale = gen-2 =
//      opposite parity). Packed flags u64[b][64] (one load polls 2 wgs) are
//      only a throttle; consumer validates the 8 payload LSBs and retries its
//      own 32 B if the flag beat the data. Saves ~1 MALL RT/step + removes the
//      producer stall. init pre-tags buffer1 LSB=1 so 0xAA poison / first gen
//      can't validate early.
//  No-overwrite: publishing gen g+1 data-depends on validating gen g (or, at
//  phase starts, on program-order-earlier consumption), so tag-valid g+1 from
//  ALL wgs => all reads of g done => gen g+2 overwrite of g's buffer is safe.
// ---------------------------------------------------------------------------

__device__ __forceinline__ float sigf(float x) { return 1.0f / (1.0f + expf(-x)); }

// ws: img float[2][4096] (32 KB), then flags u64[8][64] (4 KB)
#define IMG_F 8192

__global__ void init_ws(unsigned* w) {
  int i = blockIdx.x * blockDim.x + threadIdx.x;
  if (i < 4096)      w[i] = 0u;   // img buf0: LSB=0 (first use gen2, parity 1 -> reject)
  else if (i < 8192) w[i] = 1u;   // img buf1: LSB=1 (first use gen1, parity 0 -> reject)
  else if (i < 9216) w[i] = 0u;   // flags
}

// Stage 512x16 col-slice of a (512 x 2048) recurrent weight, K-MAJOR:
// Wl2[k*16 + c] = W[k][(c>>2)*H + wg*4 + (c&3)]
__device__ __forceinline__ void load_wk(const float* __restrict__ W, int wg,
                                        float* __restrict__ Wl2) {
  for (int idx = threadIdx.x; idx < H_ * NGC; idx += NTHR) {
    int k = idx >> 4, c = idx & 15;
    Wl2[idx] = W[k * G_ + ((c >> 2) * H_ + wg * NCOL + (c & 3))];
  }
}

// Per-lane register weights: wrk[kk*4+cg] = W rows l*8+kk, cols cg*4..cg*4+3
__device__ __forceinline__ void load_wrk(const float* __restrict__ Wl2, int l,
                                         float4* __restrict__ wrk) {
#pragma unroll
  for (int kk = 0; kk < 8; ++kk) {
    const float4* pw = (const float4*)(Wl2 + (l * 8 + kk) * 16);
    wrk[kk * 4 + 0] = pw[0];
    wrk[kk * 4 + 1] = pw[1];
    wrk[kk * 4 + 2] = pw[2];
    wrk[kk * 4 + 3] = pw[3];
  }
}

// Throttle on packed flags, then tag-validated payload read (own 32 B), dot
// with register weights, butterfly-reduce. Returns col sum for c=bitrev4(l&15).
__device__ __forceinline__ float rec_dot(const float* __restrict__ img,
                                         const u64* __restrict__ flags,
                                         unsigned gen, int b, int l,
                                         const float4* __restrict__ wrk) {
  const u64* fl = flags + (size_t)b * 64;
  for (;;) {                                    // throttle: lane l covers wg l and l+64
    u64 f = __hip_atomic_load(&fl[l], __ATOMIC_RELAXED, __HIP_MEMORY_SCOPE_AGENT);
    if ((unsigned)f >= gen && (unsigned)(f >> 32) >= gen) break;
    __builtin_amdgcn_s_sleep(1);
  }
  const unsigned p = (gen >> 1) & 1u;
  const u64* src = (const u64*)(img + (gen & 1u) * 4096 + b * H_) + (size_t)l * 4;
  u64 v[4];
  for (;;) {                                    // validate in-band tags
    unsigned bad = 0;
#pragma unroll
    for (int j = 0; j < 4; ++j)
      v[j] = __hip_atomic_load(src + j, __ATOMIC_RELAXED, __HIP_MEMORY_SCOPE_AGENT);
#pragma unroll
    for (int j = 0; j < 4; ++j)
      bad |= ((unsigned)v[j] ^ p) | (((unsigned)(v[j] >> 32)) ^ p);
    if (!(bad & 1u)) break;
    __builtin_amdgcn_s_sleep(1);
  }
  float h8[8];
#pragma unroll
  for (int j = 0; j < 4; ++j) {
    h8[2 * j]     = __uint_as_float((unsigned)v[j]);
    h8[2 * j + 1] = __uint_as_float((unsigned)(v[j] >> 32));
  }

  float acc[16];
#pragma unroll
  for (int c = 0; c < 16; ++c) acc[c] = 0.0f;
#pragma unroll
  for (int kk = 0; kk < 8; ++kk) {
    float hv = h8[kk];
    float4 w0 = wrk[kk * 4 + 0], w1 = wrk[kk * 4 + 1];
    float4 w2 = wrk[kk * 4 + 2], w3 = wrk[kk * 4 + 3];
    acc[0]  += hv * w0.x; acc[1]  += hv * w0.y; acc[2]  += hv * w0.z; acc[3]  += hv * w0.w;
    acc[4]  += hv * w1.x; acc[5]  += hv * w1.y; acc[6]  += hv * w1.z; acc[7]  += hv * w1.w;
    acc[8]  += hv * w2.x; acc[9]  += hv * w2.y; acc[10] += hv * w2.z; acc[11] += hv * w2.w;
    acc[12] += hv * w3.x; acc[13] += hv * w3.y; acc[14] += hv * w3.z; acc[15] += hv * w3.w;
  }

  // value-halving butterfly; final c per lane = bitrev4(l&15)
  float o8[8];
#pragma unroll
  for (int j = 0; j < 8; ++j) {
    float send = (l & 1) ? acc[j] : acc[8 + j];
    float keep = (l & 1) ? acc[8 + j] : acc[j];
    o8[j] = keep + __shfl_xor(send, 1);
  }
  float o4[4];
#pragma unroll
  for (int j = 0; j < 4; ++j) {
    float send = (l & 2) ? o8[j] : o8[4 + j];
    float keep = (l & 2) ? o8[4 + j] : o8[j];
    o4[j] = keep + __shfl_xor(send, 2);
  }
  float o2[2];
#pragma unroll
  for (int j = 0; j < 2; ++j) {
    float send = (l & 4) ? o4[j] : o4[2 + j];
    float keep = (l & 4) ? o4[2 + j] : o4[j];
    o2[j] = keep + __shfl_xor(send, 4);
  }
  float send = (l & 8) ? o2[0] : o2[1];
  float keep = (l & 8) ? o2[1] : o2[0];
  float vv = keep + __shfl_xor(send, 8);
  vv += __shfl_xor(vv, 16);
  vv += __shfl_xor(vv, 32);
  return vv;
}

// X[c][r] = sum_e emb[r][e]*Wih[e][col(c)] + bias[col(c)], r = t*8+b, col-major.
__device__ __forceinline__ void compute_X(const float* __restrict__ Wih,
                                          const float* __restrict__ bias,
                                          const int* __restrict__ tokens,
                                          const float* __restrict__ embed,
                                          int wg, float* __restrict__ Wbuf,
                                          float* __restrict__ Xlds,
                                          float* __restrict__ bias_lds) {
  const int tid = threadIdx.x;
  for (int idx = tid; idx < E_ * NGC; idx += NTHR) {     // 4096
    int e = idx >> 4, c = idx & 15;
    Wbuf[idx] = Wih[e * G_ + ((c >> 2) * H_ + wg * NCOL + (c & 3))];
  }
  if (tid < NGC) bias_lds[tid] = bias[(tid >> 2) * H_ + wg * NCOL + (tid & 3)];
  __syncthreads();

  const float4* er[2];
#pragma unroll
  for (int rr = 0; rr < 2; ++rr) {
    int r = tid + rr * NTHR;
    int tok = tokens[(r & 7) * T_ + (r >> 3)];           // tokens (B,T); r = t*8+b
    er[rr] = (const float4*)(embed + (size_t)tok * E_);
  }
  float acc[2][NGC];
#pragma unroll
  for (int rr = 0; rr < 2; ++rr)
#pragma unroll
    for (int cc = 0; cc < NGC; ++cc) acc[rr][cc] = bias_lds[cc];

  for (int ec = 0; ec < E_ / 4; ++ec) {
    float4 ev[2];
#pragma unroll
    for (int rr = 0; rr < 2; ++rr) ev[rr] = er[rr][ec];
    const float4* w4 = (const float4*)(Wbuf + ec * 64);  // 4 e's x 16 c
#pragma unroll
    for (int eo = 0; eo < 4; ++eo) {
      float wrow[16];
      *(float4*)(wrow + 0)  = w4[eo * 4 + 0];            // broadcast LDS reads
      *(float4*)(wrow + 4)  = w4[eo * 4 + 1];
      *(float4*)(wrow + 8)  = w4[eo * 4 + 2];
      *(float4*)(wrow + 12) = w4[eo * 4 + 3];
#pragma unroll
      for (int cc = 0; cc < NGC; ++cc) {
#pragma unroll
        for (int rr = 0; rr < 2; ++rr)
          acc[rr][cc] += reinterpret_cast<const float*>(&ev[rr])[eo] * wrow[cc];
      }
    }
  }
#pragma unroll
  for (int rr = 0; rr < 2; ++rr) {
    int r = tid + rr * NTHR;
#pragma unroll
    for (int cc = 0; cc < NGC; ++cc)
      Xlds[cc * XPITCH + r] = acc[rr][cc];               // conflict-free writes
  }
}

__attribute__((amdgpu_waves_per_eu(2, 2)))               // 8 waves = 2/EU -> 256-reg budget
__global__ __launch_bounds__(NTHR) void lstm_all(
    const int* __restrict__ tokens, const float* __restrict__ embed,
    const float* __restrict__ Wih_s, const float* __restrict__ Whh_s,
    const float* __restrict__ b_s,
    const float* __restrict__ Wih_t, const float* __restrict__ Whh_t,
    const float* __restrict__ Wmh_t, const float* __restrict__ b_t,
    float* __restrict__ out, float* __restrict__ ws) {
  __shared__ float Wl2[H_ * NGC];        // 32 KB k-major weights / Wih staging
  __shared__ float Xlds[NGC * XPITCH];   // 65.6 KB col-major X
  __shared__ float bias_lds[NGC];

  const int tid = threadIdx.x;
  const int wg  = blockIdx.x;
  const int l   = tid & 63;              // lane
  const int b   = tid >> 6;              // wave = batch
  float* img   = ws;                     // float[2][4096]
  u64*   flags = (u64*)(ws + IMG_F);     // u64[8][64]

  // lane's owned gate column c = bitrev4(l&15); quad -> output col jj
  const int cown = ((l & 1) << 3) | ((l & 2) << 1) | ((l & 4) >> 1) | ((l & 8) >> 3);
  const int p    = l & 3;
  const int qd   = (l >> 2) & 3;
  const int jj   = ((qd & 1) << 1) | (qd >> 1);   // bitrev2(qd)
  const bool st_lane = (l < 16) && (p == 0);      // lanes 0,4,8,12 -> cols {0,2,1,3}
  unsigned* myflag = (unsigned*)(flags + (size_t)0 * 64) + 0;  // set per store below

  float4 wrk[32];   // 128 VGPRs: W[l*8..+8)[0..16)

  // ---------------- Phase A1: X1 = emb @ Wih_s + b_s
  compute_X(Wih_s, b_s, tokens, embed, wg, Wl2, Xlds, bias_lds);
  __syncthreads();
  load_wk(Whh_s, wg, Wl2);
  __syncthreads();
  load_wrk(Wl2, l, wrk);

  // ---------------- Phase B: shared LSTM (only h_last live); gens 1..128
  float c_reg = 0.0f;
  for (int t = 0; t < T_; ++t) {
    float d = (t > 0) ? rec_dot(img, flags, (unsigned)t, b, l, wrk) : 0.0f;
    float pre = d + Xlds[cown * XPITCH + t * 8 + b];
    float v1 = __shfl_xor(pre, 1), v2 = __shfl_xor(pre, 2), v3 = __shfl_xor(pre, 3);
    auto pick = [&](int m) { return m == 0 ? pre : (m == 1 ? v1 : (m == 2 ? v2 : v3)); };
    float gi = pick(p ^ 0), gg = pick(p ^ 1), gf = pick(p ^ 2), go = pick(p ^ 3);
    float cn = sigf(gf) * c_reg + sigf(gi) * tanhf(gg);
    float hn = sigf(go) * tanhf(cn);
    c_reg = cn;
    const unsigned gw = (unsigned)t + 1u;
    const unsigned pn = (gw >> 1) & 1u;
    if (st_lane) {
      unsigned hb = (__float_as_uint(hn) & ~1u) | pn;    // in-band parity tag
      __hip_atomic_store((unsigned*)(img + (gw & 1u) * 4096 + b * H_ + wg * NCOL + jj),
                         hb, __ATOMIC_RELAXED, __HIP_MEMORY_SCOPE_AGENT);
    }
    if (l == 0) {                                        // flag: throttle only, no drain
      unsigned* fp = (unsigned*)(flags + (size_t)b * 64 + (wg & 63)) + (wg >> 6);
      __hip_atomic_store(fp, gw, __ATOMIC_RELAXED, __HIP_MEMORY_SCOPE_AGENT);
    }
  }

  // ---------------- M = h_last @ Wmh_t (consume gen 128)
  __syncthreads();
  load_wk(Wmh_t, wg, Wl2);
  __syncthreads();
  load_wrk(Wl2, l, wrk);
  float Mreg = rec_dot(img, flags, 128u, b, l, wrk);

  // ---------------- Phase A2: X2 = emb @ Wih_t + b_t
  __syncthreads();
  compute_X(Wih_t, b_t, tokens, embed, wg, Wl2, Xlds, bias_lds);
  __syncthreads();
  load_wk(Whh_t, wg, Wl2);
  __syncthreads();
  load_wrk(Wl2, l, wrk);

  // ---------------- Phase C: task LSTM; gens 129..255; out every step
  c_reg = 0.0f;
  for (int t = 0; t < T_; ++t) {
    float d = (t > 0) ? rec_dot(img, flags, 128u + (unsigned)t, b, l, wrk) : 0.0f;
    float pre = d + Xlds[cown * XPITCH + t * 8 + b] + Mreg;
    float v1 = __shfl_xor(pre, 1), v2 = __shfl_xor(pre, 2), v3 = __shfl_xor(pre, 3);
    auto pick = [&](int m) { return m == 0 ? pre : (m == 1 ? v1 : (m == 2 ? v2 : v3)); };
    float gi = pick(p ^ 0), gg = pick(p ^ 1), gf = pick(p ^ 2), go = pick(p ^ 3);
    float cn = sigf(gf) * c_reg + sigf(gi) * tanhf(gg);
    float hn = sigf(go) * tanhf(cn);
    c_reg = cn;
    if (st_lane) {
      out[b * (T_ * H_) + t * H_ + wg * NCOL + jj] = hn;   // untagged output
      if (t < T_ - 1) {
        const unsigned gw = 129u + (unsigned)t;
        const unsigned pn = (gw >> 1) & 1u;
        unsigned hb = (__float_as_uint(hn) & ~1u) | pn;
        __hip_atomic_store((unsigned*)(img + (gw & 1u) * 4096 + b * H_ + wg * NCOL + jj),
                           hb, __ATOMIC_RELAXED, __HIP_MEMORY_SCOPE_AGENT);
      }
    }
    if (l == 0 && t < T_ - 1) {
      unsigned* fp = (unsigned*)(flags + (size_t)b * 64 + (wg & 63)) + (wg >> 6);
      __hip_atomic_store(fp, 129u + (unsigned)t, __ATOMIC_RELAXED,
                         __HIP_MEMORY_SCOPE_AGENT);
    }
  }
  (void)myflag;
}

extern "C" void kernel_launch(void* const* d_in, const int* in_sizes, int n_in,
                              void* d_out, int out_size, void* d_ws, size_t ws_size,
                              hipStream_t stream) {
  const int*   tokens = (const int*)d_in[0];
  // d_in[1] = TASK (unused)
  const float* embed  = (const float*)d_in[2];
  const float* Wih_s  = (const float*)d_in[3];
  const float* Whh_s  = (const float*)d_in[4];
  const float* b_s    = (const float*)d_in[5];
  // d_in[6..9] = Ws_w, Ws_b, Us_w, Us_b -> dead (attention collapses)
  const float* Wih_t  = (const float*)d_in[10];
  const float* Whh_t  = (const float*)d_in[11];
  const float* Wmh_t  = (const float*)d_in[12];
  const float* b_t    = (const float*)d_in[13];
  float* out = (float*)d_out;
  float* ws  = (float*)d_ws;

  hipLaunchKernelGGL(init_ws, dim3(9), dim3(1024), 0, stream, (unsigned*)ws);
  hipLaunchKernelGGL(lstm_all, dim3(NWG), dim3(NTHR), 0, stream,
                     tokens, embed, Wih_s, Whh_s, b_s,
                     Wih_t, Whh_t, Wmh_t, b_t, out, ws);
}

// Round 8
// 758.613 us; speedup vs baseline: 4.1015x; 3.4356x over previous
//
#include <hip/hip_runtime.h>
#include <math.h>

// Problem constants (from reference)
#define B_   8
#define T_   128
#define E_   256
#define H_   512
#define G_   2048
#define NWG  256           // 1 WG per CU (forced by 148KB LDS), all co-resident
#define NTHR 512           // 8 waves
#define XP   130           // Xl pitch in ushorts (bank-spread)

typedef unsigned int u32;

// ---------------------------------------------------------------------------
// ALGEBRA (unchanged): softmax sums to 1 over t and h_shared is t-invariant =>
// Rt == h_last; attention path dead. Remaining per batch b (INDEPENDENT!):
//   h_last = sharedLSTM(emb[b]); M = h_last @ Wmh_t; out[b] = taskLSTM(...)
//
// R8 STRUCTURAL CHANGE: batches are independent -> 8 independent rings of 32
// WGs (ring = blockIdx&7, slot = blockIdx>>3 owns h-cols 16s..16s+15). No
// grid-wide sync at all. Exchange per ring: img[gen&1][b][512] floats with
// in-band mantissa-LSB parity tag (gen>>1)&1; each thread poll-loads exactly
// ITS h float (4B agent-relaxed) until the tag matches -> the poll IS the
// data read (1 MALL hop, no flags, no producer vmcnt drain). Traffic/round =
// 2KB/WG (R3's failure was 16KB/WG redundant reads -> MALL saturation).
// No-lap: a WG publishes gen g+1 only after validating gen g, so tag-valid
// g+1 everywhere => all reads of g done => overwriting g's buffer (gen g+2,
// opposite parity) is safe. Buffers init: buf0 LSB=0, buf1 LSB=1.
//
// Dot: Whh slice k-major in LDS (128KB); each lane PINS its 64 weights in
// VGPRs via asm("+v") (R4-R7 lesson: allocator remats LDS-sourced arrays
// unless pinned; 64+~40 regs fits the ~104 the allocator already grants).
// X staged bf16 in LDS (fits 160KB: 128K W + 16.6K X + 4K h/part).
// ---------------------------------------------------------------------------

__device__ __forceinline__ float sigf(float x) { return 1.0f / (1.0f + expf(-x)); }

__device__ __forceinline__ unsigned short f2bf(float x) {
  u32 u = __float_as_uint(x);
  u += 0x7fffu + ((u >> 16) & 1u);
  return (unsigned short)(u >> 16);
}
__device__ __forceinline__ float bf2f(unsigned short s) {
  return __uint_as_float(((u32)s) << 16);
}

// img: u32[2][8][512] = 32KB at ws start
__global__ void init_ws(u32* w) {
  int i = blockIdx.x * blockDim.x + threadIdx.x;
  if (i < 4096)      w[i] = 0u;   // buf0: tag 0
  else if (i < 8192) w[i] = 1u;   // buf1: tag 1
}

// Stage k-major slice: Wl[k*64+c] = W[k][(c>>4)*H + s*16 + (c&15)], k < rows
__device__ __forceinline__ void stage_W(const float* __restrict__ W, int rows,
                                        int s, float* __restrict__ Wl) {
  for (int idx = threadIdx.x; idx < rows * 64; idx += NTHR) {
    int k = idx >> 6, c = idx & 63;
    Wl[idx] = W[k * G_ + ((c >> 4) * H_ + s * 16 + (c & 15))];
  }
}

__attribute__((amdgpu_waves_per_eu(2)))
__global__ __launch_bounds__(NTHR, 1) void lstm_all(
    const int* __restrict__ tokens, const float* __restrict__ embed,
    const float* __restrict__ Wih_s, const float* __restrict__ Whh_s,
    const float* __restrict__ b_s,
    const float* __restrict__ Wih_t, const float* __restrict__ Whh_t,
    const float* __restrict__ Wmh_t, const float* __restrict__ b_t,
    float* __restrict__ out, u32* __restrict__ img) {
  __shared__ float Wl[H_ * 64];             // 128 KB, k-major weight slice
  __shared__ unsigned short Xl[64 * XP];    // 16.25 KB, bf16 X[c][t]
  __shared__ float h_lds[H_];               // staged h
  __shared__ float part[NTHR];              // dot partials [q][c]

  const int tid = threadIdx.x;
  const int l   = tid & 63;                 // lane: gate-col c = l in dot/gates
  const int wv  = tid >> 6;                 // wave: k-octant q in dot
  const int b   = blockIdx.x & 7;           // ring = batch (XCD-aligned typ.)
  const int s   = blockIdx.x >> 3;          // slot: h-cols 16s..16s+15
  const int p4  = l >> 4;                   // gate index of this lane's col

  float wreg[64];                           // pinned per-lane weight K-slice

  // ---- X phase: Xl[c][t] (bf16) = emb[b,t] @ Wih[:,col(c)] + bias[col(c)]
  auto computeX = [&](const float* __restrict__ Wih, const float* __restrict__ bias) {
    stage_W(Wih, E_, s, Wl);                // 256x64 into Wl (fits)
    __syncthreads();
    const int t = tid >> 2, grp = tid & 3;  // grp = gate; 16 cols each
    const int tok = tokens[b * T_ + t];
    const float4* er = (const float4*)(embed + (size_t)tok * E_);
    float acc[16];
#pragma unroll
    for (int j = 0; j < 16; ++j) acc[j] = bias[grp * H_ + s * 16 + j];
    for (int e4 = 0; e4 < E_ / 4; ++e4) {
      float4 em = er[e4];
#pragma unroll
      for (int eo = 0; eo < 4; ++eo) {
        float ev = reinterpret_cast<const float*>(&em)[eo];
        const float* wr = Wl + (e4 * 4 + eo) * 64 + grp * 16;  // broadcast reads
#pragma unroll
        for (int j = 0; j < 16; ++j) acc[j] += ev * wr[j];
      }
    }
#pragma unroll
    for (int j = 0; j < 16; ++j) Xl[(grp * 16 + j) * XP + t] = f2bf(acc[j]);
  };

  auto load_wreg = [&] {
#pragma unroll
    for (int kk = 0; kk < 64; ++kk) wreg[kk] = Wl[(wv * 64 + kk) * 64 + l];
#pragma unroll
    for (int kk = 0; kk < 64; ++kk) asm volatile("" : "+v"(wreg[kk]));  // pin
  };

  auto do_dot = [&]() -> float {            // partial over k in [wv*64, wv*64+64)
    float a0 = 0.f, a1 = 0.f, a2 = 0.f, a3 = 0.f;
    const float4* h4 = (const float4*)(h_lds + wv * 64);
#pragma unroll
    for (int kk = 0; kk < 16; ++kk) {
      float4 hv = h4[kk];                   // broadcast (all lanes same addr)
      a0 += hv.x * wreg[kk * 4 + 0];
      a1 += hv.y * wreg[kk * 4 + 1];
      a2 += hv.z * wreg[kk * 4 + 2];
      a3 += hv.w * wreg[kk * 4 + 3];
    }
    return (a0 + a1) + (a2 + a3);
  };

  auto poll_stage = [&](unsigned gen) {     // poll OWN float until tag matches
    const u32 par = (gen >> 1) & 1u;
    const u32* src = img + (gen & 1u) * 4096 + b * H_ + tid;
    u32 u;
    while (((u = __hip_atomic_load(src, __ATOMIC_RELAXED,
                                   __HIP_MEMORY_SCOPE_AGENT)) & 1u) != par)
      __builtin_amdgcn_s_sleep(1);
    h_lds[tid] = __uint_as_float(u);        // keep tag bit (1 ulp, harmless)
  };

  // ---------------- Phase A1 + shared weights
  computeX(Wih_s, b_s);
  __syncthreads();
  stage_W(Whh_s, H_, s, Wl);
  __syncthreads();
  load_wreg();

  float c_reg = 0.f, Mreg = 0.f;

  // ---------------- Phase B: shared LSTM; publishes gens 1..128
  for (int t = 0; t < T_; ++t) {
    if (t > 0) poll_stage((unsigned)t);
    __syncthreads();                         // h_lds staged (and part free)
    part[tid] = (t > 0) ? do_dot() : 0.f;
    __syncthreads();                         // partials ready
    if (wv == 0) {
      float sum = 0.f;
#pragma unroll
      for (int q = 0; q < 8; ++q) sum += part[q * 64 + l];
      float pre = sum + bf2f(Xl[l * XP + t]);
      float v16 = __shfl_xor(pre, 16), v32 = __shfl_xor(pre, 32), v48 = __shfl_xor(pre, 48);
      auto pick = [&](int m) { int x = p4 ^ m; return x == 0 ? pre : (x == 1 ? v16 : (x == 2 ? v32 : v48)); };
      float gi = pick(0), gf = pick(1), gg = pick(2), go = pick(3);
      float cn = sigf(gf) * c_reg + sigf(gi) * tanhf(gg);
      float hn = sigf(go) * tanhf(cn);
      c_reg = cn;
      const unsigned gw = (unsigned)t + 1u;
      if (p4 == 0) {                         // lanes 0..15 own h-cols s*16+l
        u32 hb = (__float_as_uint(hn) & ~1u) | ((gw >> 1) & 1u);
        __hip_atomic_store(img + (gw & 1u) * 4096 + b * H_ + s * 16 + l, hb,
                           __ATOMIC_RELAXED, __HIP_MEMORY_SCOPE_AGENT);
      }
    }
  }

  // ---------------- M = h_last @ Wmh_t (consume gen 128)
  __syncthreads();
  stage_W(Wmh_t, H_, s, Wl);
  __syncthreads();
  load_wreg();
  poll_stage(128u);
  __syncthreads();
  part[tid] = do_dot();
  __syncthreads();
  if (wv == 0) {
    float sum = 0.f;
#pragma unroll
    for (int q = 0; q < 8; ++q) sum += part[q * 64 + l];
    Mreg = sum;
  }

  // ---------------- Phase A2 + task weights
  __syncthreads();
  computeX(Wih_t, b_t);
  __syncthreads();
  stage_W(Whh_t, H_, s, Wl);
  __syncthreads();
  load_wreg();

  // ---------------- Phase C: task LSTM; gens 129..255; out every step
  c_reg = 0.f;
  for (int t = 0; t < T_; ++t) {
    if (t > 0) poll_stage(128u + (unsigned)t);
    __syncthreads();
    part[tid] = (t > 0) ? do_dot() : 0.f;
    __syncthreads();
    if (wv == 0) {
      float sum = 0.f;
#pragma unroll
      for (int q = 0; q < 8; ++q) sum += part[q * 64 + l];
      float pre = sum + bf2f(Xl[l * XP + t]) + Mreg;
      float v16 = __shfl_xor(pre, 16), v32 = __shfl_xor(pre, 32), v48 = __shfl_xor(pre, 48);
      auto pick = [&](int m) { int x = p4 ^ m; return x == 0 ? pre : (x == 1 ? v16 : (x == 2 ? v32 : v48)); };
      float gi = pick(0), gf = pick(1), gg = pick(2), go = pick(3);
      float cn = sigf(gf) * c_reg + sigf(gi) * tanhf(gg);
      float hn = sigf(go) * tanhf(cn);
      c_reg = cn;
      if (p4 == 0) {
        out[b * (T_ * H_) + t * H_ + s * 16 + l] = hn;
        if (t < T_ - 1) {
          const unsigned gw = 129u + (unsigned)t;
          u32 hb = (__float_as_uint(hn) & ~1u) | ((gw >> 1) & 1u);
          __hip_atomic_store(img + (gw & 1u) * 4096 + b * H_ + s * 16 + l, hb,
                             __ATOMIC_RELAXED, __HIP_MEMORY_SCOPE_AGENT);
        }
      }
    }
  }
}

extern "C" void kernel_launch(void* const* d_in, const int* in_sizes, int n_in,
                              void* d_out, int out_size, void* d_ws, size_t ws_size,
                              hipStream_t stream) {
  const int*   tokens = (const int*)d_in[0];
  // d_in[1] = TASK (unused)
  const float* embed  = (const float*)d_in[2];
  const float* Wih_s  = (const float*)d_in[3];
  const float* Whh_s  = (const float*)d_in[4];
  const float* b_s    = (const float*)d_in[5];
  // d_in[6..9] = Ws_w, Ws_b, Us_w, Us_b -> dead (attention collapses)
  const float* Wih_t  = (const float*)d_in[10];
  const float* Whh_t  = (const float*)d_in[11];
  const float* Wmh_t  = (const float*)d_in[12];
  const float* b_t    = (const float*)d_in[13];
  float* out = (float*)d_out;
  u32*   img = (u32*)d_ws;

  hipLaunchKernelGGL(init_ws, dim3(8), dim3(1024), 0, stream, img);
  hipLaunchKernelGGL(lstm_all, dim3(NWG), dim3(NTHR), 0, stream,
                     tokens, embed, Wih_s, Whh_s, b_s,
                     Wih_t, Whh_t, Wmh_t, b_t, out, img);
}